// Round 9
// baseline (389.678 us; speedup 1.0000x reference)
//
#include <hip/hip_runtime.h>
#include <cstdint>

typedef unsigned short u16;
typedef _Float16 f16;
typedef __attribute__((ext_vector_type(8))) short    s8v;  // 8 bf16 (4 VGPRs)
typedef __attribute__((ext_vector_type(8))) _Float16 h8v;  // 8 fp16 (4 VGPRs)
typedef __attribute__((ext_vector_type(4))) float    f4v;

__device__ __forceinline__ float bf2f(u16 b) {
  unsigned int u = ((unsigned int)b) << 16;
  float f;
  __builtin_memcpy(&f, &u, 4);
  return f;
}
__device__ __forceinline__ u16 f2bf(float f) {
  unsigned int u;
  __builtin_memcpy(&u, &f, 4);
  u += 0x7fffu + ((u >> 16) & 1u);   // RNE (finite inputs only)
  return (u16)(u >> 16);
}

// async global->LDS, 16B per lane; LDS dest = wave-uniform base + lane*16
__device__ __forceinline__ void glds16(const void* g, void* l) {
  __builtin_amdgcn_global_load_lds(
      (const __attribute__((address_space(1))) unsigned int*)g,
      (__attribute__((address_space(3))) unsigned int*)l, 16, 0, 0);
}

#define BM 128
#define BN 128
// BK=64 as two BK=32 subtiles. LDS XOR swizzle: element (row, kchunk c) lives at
// row*32 + (c ^ ((row>>1)&3))*8 -> fragment reads spread 8 bank-groups (2-way, free)
// instead of 2 (8-way). Write side: lane fetches k-chunk (lane&3)^((lane>>3)&3).

// ---------------- dtype detector (flg[0]=1: fp32 storage, 0: bf16) ----------------
__global__ __launch_bounds__(256)
void detect_dtype(const u16* __restrict__ q, int* __restrict__ flg)
{
  __shared__ int cbig, czero;
  if (threadIdx.x == 0) { cbig = 0; czero = 0; }
  __syncthreads();
  int b = 0, z = 0;
  for (int i = threadIdx.x; i < 4096; i += 256) {
    float v = bf2f(q[i]);
    if (!(fabsf(v) < 1e4f)) b++;
    if ((i & 1) == 0 && q[i] == 0) z++;
  }
  atomicAdd(&cbig, b);
  atomicAdd(&czero, z);
  __syncthreads();
  if (threadIdx.x == 0) flg[0] = (cbig > 64 || czero > 1600) ? 1 : 0;
}

// ---------------- inputs -> fp16 plane (query & kv in one launch) ----------------
__global__ __launch_bounds__(256)
void convert_h(const int* __restrict__ flg,
               const void* __restrict__ q, const void* __restrict__ kv,
               f16* __restrict__ qo, f16* __restrict__ kvo, long n)
{
  const void* in = blockIdx.y ? kv : q;
  f16* out = blockIdx.y ? kvo : qo;
  const long i = ((long)blockIdx.x * 256 + threadIdx.x) * 8;
  if (i >= n) return;
  h8v h;
  if (flg[0] != 0) {
    const float* p = (const float*)in + i;
    f4v f0 = *(const f4v*)p;
    f4v f1 = *(const f4v*)(p + 4);
#pragma unroll
    for (int j = 0; j < 4; ++j) {
      h[j]     = (f16)f0[j];
      h[4 + j] = (f16)f1[j];
    }
  } else {
    s8v b = *(const s8v*)((const short*)in + i);
#pragma unroll
    for (int j = 0; j < 8; ++j) h[j] = (f16)bf2f((u16)b[j]);
  }
  *(h8v*)(out + i) = h;
}

// ---------------- four W^T in one launch: z<3 -> fp16 (Wq,Wk,Wv); z=3 -> bf16 (Wo) ----
__global__ __launch_bounds__(256)
void transpose_w4(const int* __restrict__ flg,
                  const void* __restrict__ w0, const void* __restrict__ w1,
                  const void* __restrict__ w2, const void* __restrict__ w3,
                  f16* __restrict__ h0, f16* __restrict__ h1,
                  f16* __restrict__ h2, u16* __restrict__ b3, int D)
{
  __shared__ float tile[32][33];
  const int zb = blockIdx.z;
  const void* in_v = (zb == 0) ? w0 : (zb == 1) ? w1 : (zb == 2) ? w2 : w3;
  const bool i32 = (flg[0] != 0);
  const u16*   in16 = (const u16*)in_v;
  const float* in32 = (const float*)in_v;
  const int c0 = blockIdx.x * 32, r0 = blockIdx.y * 32;
  const int tx = threadIdx.x, ty = threadIdx.y;   // block (32,8)
  for (int i = ty; i < 32; i += 8) {
    const long idx = (long)(r0 + i) * D + c0 + tx;
    tile[i][tx] = i32 ? in32[idx] : bf2f(in16[idx]);
  }
  __syncthreads();
  f16* outH = (zb == 0) ? h0 : (zb == 1) ? h1 : h2;
  for (int i = ty; i < 32; i += 8) {
    const long idx = (long)(c0 + i) * D + r0 + tx;
    const float v = tile[tx][i];
    if (zb == 3) b3[idx]   = f2bf(v);
    else         outH[idx] = (f16)v;
  }
}

// ---------------- Q/K/V projections in one z=3 dispatch (fp16, BK=64) ----------------
__global__ __launch_bounds__(256)
void gemm_proj3(const int* __restrict__ flg,
                const f16* __restrict__ Qi, const f16* __restrict__ KVi,
                const f16* __restrict__ WqT, const f16* __restrict__ WkT,
                const f16* __restrict__ WvT,
                const void* __restrict__ bq, const void* __restrict__ bk,
                const void* __restrict__ bv,
                f16* __restrict__ Qf, f16* __restrict__ Kf,
                u16* __restrict__ Vt, int M, int N, int K, int SB)
{
  __shared__ u16 As[BM * 64];   // two 128x32 subtiles, XOR-swizzled k-chunks
  __shared__ u16 Bs[BN * 64];

  const int zb = blockIdx.z;
  const f16* A = (zb == 0) ? Qi : KVi;
  const f16* B = (zb == 0) ? WqT : (zb == 1) ? WkT : WvT;
  const void* bias = (zb == 0) ? bq : (zb == 1) ? bk : bv;

  const int f_in = flg[0];
  const int tid = threadIdx.x, lane = tid & 63, wave = tid >> 6;
  const int wm = wave >> 1, wn = wave & 1;
  const int m0 = blockIdx.y * BM, n0 = blockIdx.x * BN;

  const int rr  = wave * 32 + (lane >> 2);
  const int cc8 = 8 * ((lane & 3) ^ ((lane >> 3) & 3));   // swizzled k-chunk fetch
  const f16* ga00 = A + (long)(m0 + rr) * K + cc8;
  const f16* ga01 = ga00 + 16 * (long)K;
  const f16* gb00 = B + (long)(n0 + rr) * K + cc8;
  const f16* gb01 = gb00 + 16 * (long)K;
  u16* la0 = &As[(wave * 2) * 512];  u16* la1 = la0 + 512;
  u16* lb0 = &Bs[(wave * 2) * 512];  u16* lb1 = lb0 + 512;

  f4v acc[4][4];
#pragma unroll
  for (int i = 0; i < 4; ++i)
#pragma unroll
    for (int j = 0; j < 4; ++j) acc[i][j] = (f4v){0.f, 0.f, 0.f, 0.f};

  const int fr  = lane & 15;
  const int fks = 8 * (((lane >> 4) ^ (lane >> 1)) & 3);  // swizzled fragment offset
  const int aoff = (wm * 64 + fr) * 32 + fks;
  const int boff = (wn * 64 + fr) * 32 + fks;

  for (int kt = 0; kt < K; kt += 64) {
    glds16(ga00,      la0);        glds16(ga01,      la1);
    glds16(ga00 + 32, la0 + 4096); glds16(ga01 + 32, la1 + 4096);
    glds16(gb00,      lb0);        glds16(gb01,      lb1);
    glds16(gb00 + 32, lb0 + 4096); glds16(gb01 + 32, lb1 + 4096);
    ga00 += 64; ga01 += 64; gb00 += 64; gb01 += 64;
    __syncthreads();

    {
      h8v af[4], bfr[4];
#pragma unroll
      for (int mi = 0; mi < 4; ++mi) af[mi]  = *(const h8v*)&As[aoff + mi * 512];
#pragma unroll
      for (int ni = 0; ni < 4; ++ni) bfr[ni] = *(const h8v*)&Bs[boff + ni * 512];
#pragma unroll
      for (int mi = 0; mi < 4; ++mi)
#pragma unroll
        for (int ni = 0; ni < 4; ++ni)
          acc[mi][ni] = __builtin_amdgcn_mfma_f32_16x16x32_f16(af[mi], bfr[ni], acc[mi][ni], 0, 0, 0);
    }
    {
      h8v af[4], bfr[4];
#pragma unroll
      for (int mi = 0; mi < 4; ++mi) af[mi]  = *(const h8v*)&As[4096 + aoff + mi * 512];
#pragma unroll
      for (int ni = 0; ni < 4; ++ni) bfr[ni] = *(const h8v*)&Bs[4096 + boff + ni * 512];
#pragma unroll
      for (int mi = 0; mi < 4; ++mi)
#pragma unroll
        for (int ni = 0; ni < 4; ++ni)
          acc[mi][ni] = __builtin_amdgcn_mfma_f32_16x16x32_f16(af[mi], bfr[ni], acc[mi][ni], 0, 0, 0);
    }
    __syncthreads();
  }

  const int cr = (lane >> 4) * 4, ccl = lane & 15;
  if (zb < 2) {
    f16* out = zb ? Kf : Qf;
#pragma unroll
    for (int ni = 0; ni < 4; ++ni) {
      const int gcol = n0 + wn * 64 + ni * 16 + ccl;
      const float bvv = (f_in != 0) ? ((const float*)bias)[gcol]
                                    : bf2f(((const u16*)bias)[gcol]);
#pragma unroll
      for (int mi = 0; mi < 4; ++mi)
#pragma unroll
        for (int r = 0; r < 4; ++r) {
          const long grow = (long)(m0 + wm * 64 + mi * 16 + cr + r);
          out[grow * N + gcol] = (f16)(acc[mi][ni][r] + bvv);
        }
    }
  } else {
    // transposed epilogue through dead staging LDS
    u16* xw = (wave < 2) ? (&As[0] + wave * 2176) : (&Bs[0] + (wave - 2) * 2176);
    const int b  = m0 / SB;
    const int s0 = (m0 % SB) + wm * 64;
    const long bbase = (long)b * N * SB;
#pragma unroll
    for (int h = 0; h < 2; ++h) {
#pragma unroll
      for (int nl = 0; nl < 2; ++nl) {
        const int ni = h * 2 + nl;
        const int gcol = n0 + wn * 64 + ni * 16 + ccl;
        const float bvv = (f_in != 0) ? ((const float*)bias)[gcol]
                                      : bf2f(((const u16*)bias)[gcol]);
#pragma unroll
        for (int mi = 0; mi < 4; ++mi)
#pragma unroll
          for (int r = 0; r < 4; ++r)
            xw[(mi * 16 + cr + r) * 34 + nl * 16 + ccl] = f2bf(acc[mi][ni][r] + bvv);
      }
      __syncthreads();
#pragma unroll
      for (int c = 0; c < 32; ++c) {
        const int gcol = n0 + wn * 64 + h * 32 + c;
        Vt[bbase + (long)gcol * SB + s0 + lane] = xw[lane * 34 + c];
      }
      __syncthreads();
    }
  }
}

// ---------------- scores GEMM: fp16, BK=64, fp32 out, z-batched ----------------
__global__ __launch_bounds__(256)
void gemm_sc64(const f16* __restrict__ A, const f16* __restrict__ B,
               float* __restrict__ C, int M, int N, int K,
               long sA, long sB, long sC)
{
  __shared__ u16 As[BM * 64];
  __shared__ u16 Bs[BN * 64];

  const int tid = threadIdx.x, lane = tid & 63, wave = tid >> 6;
  const int wm = wave >> 1, wn = wave & 1;
  const int m0 = blockIdx.y * BM, n0 = blockIdx.x * BN;
  const long z = blockIdx.z;

  const int rr  = wave * 32 + (lane >> 2);
  const int cc8 = 8 * ((lane & 3) ^ ((lane >> 3) & 3));
  const f16* ga00 = A + (long)(m0 + rr) * K + cc8 + z * sA;
  const f16* ga01 = ga00 + 16 * (long)K;
  const f16* gb00 = B + (long)(n0 + rr) * K + cc8 + z * sB;
  const f16* gb01 = gb00 + 16 * (long)K;
  u16* la0 = &As[(wave * 2) * 512];  u16* la1 = la0 + 512;
  u16* lb0 = &Bs[(wave * 2) * 512];  u16* lb1 = lb0 + 512;

  f4v acc[4][4];
#pragma unroll
  for (int i = 0; i < 4; ++i)
#pragma unroll
    for (int j = 0; j < 4; ++j) acc[i][j] = (f4v){0.f, 0.f, 0.f, 0.f};

  const int fr  = lane & 15;
  const int fks = 8 * (((lane >> 4) ^ (lane >> 1)) & 3);
  const int aoff = (wm * 64 + fr) * 32 + fks;
  const int boff = (wn * 64 + fr) * 32 + fks;

  for (int kt = 0; kt < K; kt += 64) {
    glds16(ga00,      la0);        glds16(ga01,      la1);
    glds16(ga00 + 32, la0 + 4096); glds16(ga01 + 32, la1 + 4096);
    glds16(gb00,      lb0);        glds16(gb01,      lb1);
    glds16(gb00 + 32, lb0 + 4096); glds16(gb01 + 32, lb1 + 4096);
    ga00 += 64; ga01 += 64; gb00 += 64; gb01 += 64;
    __syncthreads();

    {
      h8v af[4], bfr[4];
#pragma unroll
      for (int mi = 0; mi < 4; ++mi) af[mi]  = *(const h8v*)&As[aoff + mi * 512];
#pragma unroll
      for (int ni = 0; ni < 4; ++ni) bfr[ni] = *(const h8v*)&Bs[boff + ni * 512];
#pragma unroll
      for (int mi = 0; mi < 4; ++mi)
#pragma unroll
        for (int ni = 0; ni < 4; ++ni)
          acc[mi][ni] = __builtin_amdgcn_mfma_f32_16x16x32_f16(af[mi], bfr[ni], acc[mi][ni], 0, 0, 0);
    }
    {
      h8v af[4], bfr[4];
#pragma unroll
      for (int mi = 0; mi < 4; ++mi) af[mi]  = *(const h8v*)&As[4096 + aoff + mi * 512];
#pragma unroll
      for (int ni = 0; ni < 4; ++ni) bfr[ni] = *(const h8v*)&Bs[4096 + boff + ni * 512];
#pragma unroll
      for (int mi = 0; mi < 4; ++mi)
#pragma unroll
        for (int ni = 0; ni < 4; ++ni)
          acc[mi][ni] = __builtin_amdgcn_mfma_f32_16x16x32_f16(af[mi], bfr[ni], acc[mi][ni], 0, 0, 0);
    }
    __syncthreads();
  }

  const int cr = (lane >> 4) * 4, ccl = lane & 15;
#pragma unroll
  for (int ni = 0; ni < 4; ++ni) {
    const int gcol = n0 + wn * 64 + ni * 16 + ccl;
#pragma unroll
    for (int mi = 0; mi < 4; ++mi)
#pragma unroll
      for (int r = 0; r < 4; ++r) {
        const long grow = (long)(m0 + wm * 64 + mi * 16 + cr + r);
        C[z * sC + grow * N + gcol] = acc[mi][ni][r];
      }
  }
}

// ---------------- bf16 NT GEMM, BK=64 (PV, out-proj) ----------------
template<bool OUT_FLAG, bool HAS_BIAS>
__global__ __launch_bounds__(256)
void gemm_bf64(const int* __restrict__ flg, const u16* __restrict__ A,
               const u16* __restrict__ Bt, const void* __restrict__ bias,
               void* __restrict__ Cv, int M, int N, int K,
               long sA, long sB, long sC)
{
  __shared__ u16 As[BM * 64];
  __shared__ u16 Bs[BN * 64];

  const int f_in = flg[0];
  const int tid = threadIdx.x, lane = tid & 63, wave = tid >> 6;
  const int wm = wave >> 1, wn = wave & 1;
  const int m0 = blockIdx.y * BM, n0 = blockIdx.x * BN;
  const long z = blockIdx.z;

  const int rr  = wave * 32 + (lane >> 2);
  const int cc8 = 8 * ((lane & 3) ^ ((lane >> 3) & 3));
  const u16* ga00 = A + (long)(m0 + rr) * K + cc8 + z * sA;
  const u16* ga01 = ga00 + 16 * (long)K;
  const u16* gb00 = Bt + (long)(n0 + rr) * K + cc8 + z * sB;
  const u16* gb01 = gb00 + 16 * (long)K;
  u16* la0 = &As[(wave * 2) * 512];  u16* la1 = la0 + 512;
  u16* lb0 = &Bs[(wave * 2) * 512];  u16* lb1 = lb0 + 512;

  f4v acc[4][4];
#pragma unroll
  for (int i = 0; i < 4; ++i)
#pragma unroll
    for (int j = 0; j < 4; ++j) acc[i][j] = (f4v){0.f, 0.f, 0.f, 0.f};

  const int fr  = lane & 15;
  const int fks = 8 * (((lane >> 4) ^ (lane >> 1)) & 3);
  const int aoff = (wm * 64 + fr) * 32 + fks;
  const int boff = (wn * 64 + fr) * 32 + fks;

  for (int kt = 0; kt < K; kt += 64) {
    glds16(ga00,      la0);        glds16(ga01,      la1);
    glds16(ga00 + 32, la0 + 4096); glds16(ga01 + 32, la1 + 4096);
    glds16(gb00,      lb0);        glds16(gb01,      lb1);
    glds16(gb00 + 32, lb0 + 4096); glds16(gb01 + 32, lb1 + 4096);
    ga00 += 64; ga01 += 64; gb00 += 64; gb01 += 64;
    __syncthreads();

    {
      s8v af[4], bfr[4];
#pragma unroll
      for (int mi = 0; mi < 4; ++mi) af[mi]  = *(const s8v*)&As[aoff + mi * 512];
#pragma unroll
      for (int ni = 0; ni < 4; ++ni) bfr[ni] = *(const s8v*)&Bs[boff + ni * 512];
#pragma unroll
      for (int mi = 0; mi < 4; ++mi)
#pragma unroll
        for (int ni = 0; ni < 4; ++ni)
          acc[mi][ni] = __builtin_amdgcn_mfma_f32_16x16x32_bf16(af[mi], bfr[ni], acc[mi][ni], 0, 0, 0);
    }
    {
      s8v af[4], bfr[4];
#pragma unroll
      for (int mi = 0; mi < 4; ++mi) af[mi]  = *(const s8v*)&As[4096 + aoff + mi * 512];
#pragma unroll
      for (int ni = 0; ni < 4; ++ni) bfr[ni] = *(const s8v*)&Bs[4096 + boff + ni * 512];
#pragma unroll
      for (int mi = 0; mi < 4; ++mi)
#pragma unroll
        for (int ni = 0; ni < 4; ++ni)
          acc[mi][ni] = __builtin_amdgcn_mfma_f32_16x16x32_bf16(af[mi], bfr[ni], acc[mi][ni], 0, 0, 0);
    }
    __syncthreads();
  }

  const int cr = (lane >> 4) * 4, ccl = lane & 15;
  const bool o32 = OUT_FLAG && (f_in != 0);
#pragma unroll
  for (int ni = 0; ni < 4; ++ni) {
    const int gcol = n0 + wn * 64 + ni * 16 + ccl;
    float bvv = 0.f;
    if (HAS_BIAS)
      bvv = (f_in != 0) ? ((const float*)bias)[gcol] : bf2f(((const u16*)bias)[gcol]);
#pragma unroll
    for (int mi = 0; mi < 4; ++mi)
#pragma unroll
      for (int r = 0; r < 4; ++r) {
        const long grow = (long)(m0 + wm * 64 + mi * 16 + cr + r);
        const float val = acc[mi][ni][r] + bvv;
        const long idx = z * sC + grow * N + gcol;
        if (o32) ((float*)Cv)[idx] = val;
        else     ((u16*)Cv)[idx]   = f2bf(val);
      }
  }
}

// ---------------- row softmax fp32 -> bf16 attn, N=2048, one block/row ----------------
__global__ __launch_bounds__(256)
void softmax_rows_bf(const float* __restrict__ S, u16* __restrict__ P, int N)
{
  const float* row = S + (long)blockIdx.x * N;
  u16* prow = P + (long)blockIdx.x * N;
  const int t = threadIdx.x;
  f4v v0 = *(const f4v*)(row + t * 8);
  f4v v1 = *(const f4v*)(row + t * 8 + 4);

  float m = v0[0];
#pragma unroll
  for (int j = 1; j < 4; ++j) m = fmaxf(m, v0[j]);
#pragma unroll
  for (int j = 0; j < 4; ++j) m = fmaxf(m, v1[j]);
  for (int off = 32; off > 0; off >>= 1) m = fmaxf(m, __shfl_down(m, off, 64));

  __shared__ float redm[4], reds[4];
  if ((t & 63) == 0) redm[t >> 6] = m;
  __syncthreads();
  m = fmaxf(fmaxf(redm[0], redm[1]), fmaxf(redm[2], redm[3]));

  float s = 0.f;
#pragma unroll
  for (int j = 0; j < 4; ++j) { v0[j] = __expf(v0[j] - m); s += v0[j]; }
#pragma unroll
  for (int j = 0; j < 4; ++j) { v1[j] = __expf(v1[j] - m); s += v1[j]; }
  for (int off = 32; off > 0; off >>= 1) s += __shfl_down(s, off, 64);
  if ((t & 63) == 0) reds[t >> 6] = s;
  __syncthreads();
  s = reds[0] + reds[1] + reds[2] + reds[3];

  const float inv = 1.f / s;
  s8v o;
#pragma unroll
  for (int j = 0; j < 4; ++j) {
    o[j]     = (short)f2bf(v0[j] * inv);
    o[4 + j] = (short)f2bf(v1[j] * inv);
  }
  *(s8v*)(prow + t * 8) = o;
}

extern "C" void kernel_launch(void* const* d_in, const int* in_sizes, int n_in,
                              void* d_out, int out_size, void* d_ws, size_t ws_size,
                              hipStream_t stream)
{
  const void* query = d_in[0];
  const void* kv    = d_in[1];
  const void* Wq    = d_in[2];
  const void* bq    = d_in[3];
  const void* Wk    = d_in[4];
  const void* bk    = d_in[5];
  const void* Wv    = d_in[6];
  const void* bv    = d_in[7];
  const void* Wo    = d_in[8];
  const void* bo    = d_in[9];

  const int Bn = 4, S = 2048, D = 1024;
  const int MS = Bn * S;                       // 8192
  const size_t KBu = 1024, MBu = 1024 * 1024;
  const long nTok = (long)MS * D;

  // ---- workspace layout (~168 MB; ws proven >= 173 MB) ----
  char* ws = (char*)d_ws;
  int*  flg  = (int*)(ws);
  f16*  Qi   = (f16*)(ws + 64 * KBu);          // 16MB fp16 input tokens
  f16*  KVi  = (f16*)(ws + 64 * KBu + 16 * MBu);
  char* rW   = ws + 64 * KBu + 32 * MBu;       // 8MB: W^T
  f16*  WqT  = (f16*)(rW);
  f16*  WkT  = (f16*)(rW + 2 * MBu);
  f16*  WvT  = (f16*)(rW + 4 * MBu);
  u16*  WoT  = (u16*)(rW + 6 * MBu);
  char* rQK  = rW + 8 * MBu;                   // 32MB: Q,K fp16; later attn bf16
  f16*  Qf   = (f16*)(rQK);
  f16*  Kf   = (f16*)(rQK + 16 * MBu);
  u16*  attn = (u16*)(rQK);                    // 32MB (Q/K dead after scores)
  float* Sc  = (float*)(rQK + 32 * MBu);       // 64MB fp32 scores
  char* rV   = rQK + 96 * MBu;                 // 32MB
  u16*  Vt   = (u16*)(rV);                     // [B][D][S] bf16
  u16*  Cx   = (u16*)(rV + 16 * MBu);          // [B][S][D] bf16

  detect_dtype<<<1, 256, 0, stream>>>((const u16*)query, flg);

  convert_h<<<dim3((unsigned)(nTok / 2048), 2), 256, 0, stream>>>(
      flg, query, kv, Qi, KVi, nTok);

  dim3 tb(32, 8);
  transpose_w4<<<dim3(32, 32, 4), tb, 0, stream>>>(
      flg, Wq, Wk, Wv, Wo, WqT, WkT, WvT, WoT, D);

  // Q, K, V projections in one dispatch (V -> Vt transposed)
  gemm_proj3<<<dim3(D / BN, MS / BM, 3), 256, 0, stream>>>(
      flg, Qi, KVi, WqT, WkT, WvT, bq, bk, bv, Qf, Kf, Vt, MS, D, D, S);

  // scores (fp16, fp32 out), softmax -> bf16 attn, PV (bf16)
  gemm_sc64<<<dim3(S / BN, S / BM, Bn), 256, 0, stream>>>(
      Qf, Kf, Sc, S, S, D, (long)S * D, (long)S * D, (long)S * S);
  softmax_rows_bf<<<dim3(Bn * S), 256, 0, stream>>>(Sc, attn, S);
  gemm_bf64<false, false><<<dim3(D / BN, S / BM, Bn), 256, 0, stream>>>(
      flg, attn, Vt, nullptr, Cx, S, D, S, (long)S * S, (long)D * S, (long)S * D);

  // output projection -> d_out (dtype per flag)
  gemm_bf64<true, true><<<dim3(D / BN, MS / BM, 1), 256, 0, stream>>>(
      flg, Cx, WoT, bo, d_out, MS, D, D, 0L, 0L, 0L);
}

// Round 10
// 351.048 us; speedup vs baseline: 1.1100x; 1.1100x over previous
//
#include <hip/hip_runtime.h>
#include <cstdint>

typedef unsigned short u16;
typedef _Float16 f16;
typedef __attribute__((ext_vector_type(8))) short    s8v;  // 8 bf16 (4 VGPRs)
typedef __attribute__((ext_vector_type(8))) _Float16 h8v;  // 8 fp16 (4 VGPRs)
typedef __attribute__((ext_vector_type(4))) float    f4v;

__device__ __forceinline__ float bf2f(u16 b) {
  unsigned int u = ((unsigned int)b) << 16;
  float f;
  __builtin_memcpy(&f, &u, 4);
  return f;
}
__device__ __forceinline__ u16 f2bf(float f) {
  unsigned int u;
  __builtin_memcpy(&u, &f, 4);
  u += 0x7fffu + ((u >> 16) & 1u);   // RNE (finite inputs only)
  return (u16)(u >> 16);
}

// async global->LDS, 16B per lane; LDS dest = wave-uniform base + lane*16
__device__ __forceinline__ void glds16(const void* g, void* l) {
  __builtin_amdgcn_global_load_lds(
      (const __attribute__((address_space(1))) unsigned int*)g,
      (__attribute__((address_space(3))) unsigned int*)l, 16, 0, 0);
}

// XCD-aware swizzle: blocks sharing an A-row-tile (same by, all bx) get the same
// p%8 -> same XCD L2 (dispatch round-robin heuristic; wrong mapping = speed only).
__device__ __forceinline__ void swz_xy(int& bx, int& by) {
  const int gx = gridDim.x;
  const int p = blockIdx.y * gx + blockIdx.x;
  bx = (p >> 3) % gx;
  by = (p & 7) + 8 * (p / (gx * 8));
}

#define BM 128
#define BN 128
// BK=64 (two swizzled BK=32 subtiles) + ping-pong LDS double buffer (64KB):
// prefetch iter k+1 while MFMAing iter k; ONE barrier per iter.
// LDS XOR swizzle from r9 kept (conflicts 6.5e6 -> 2.6e5, free).

// stage one 128x64 A-tile + B-tile pair into dstA/dstB (u16 base ptrs)
#define STAGE8(dstA, dstB)                                                  \
  do {                                                                      \
    glds16(ga00,      (dstA) + l0);        glds16(ga01,      (dstA) + l1);  \
    glds16(ga00 + 32, (dstA) + l0 + 4096); glds16(ga01 + 32, (dstA) + l1 + 4096); \
    glds16(gb00,      (dstB) + l0);        glds16(gb01,      (dstB) + l1);  \
    glds16(gb00 + 32, (dstB) + l0 + 4096); glds16(gb01 + 32, (dstB) + l1 + 4096); \
    ga00 += 64; ga01 += 64; gb00 += 64; gb01 += 64;                         \
  } while (0)

// ---------------- dtype detector (flg[0]=1: fp32 storage, 0: bf16) ----------------
__global__ __launch_bounds__(256)
void detect_dtype(const u16* __restrict__ q, int* __restrict__ flg)
{
  __shared__ int cbig, czero;
  if (threadIdx.x == 0) { cbig = 0; czero = 0; }
  __syncthreads();
  int b = 0, z = 0;
  for (int i = threadIdx.x; i < 4096; i += 256) {
    float v = bf2f(q[i]);
    if (!(fabsf(v) < 1e4f)) b++;
    if ((i & 1) == 0 && q[i] == 0) z++;
  }
  atomicAdd(&cbig, b);
  atomicAdd(&czero, z);
  __syncthreads();
  if (threadIdx.x == 0) flg[0] = (cbig > 64 || czero > 1600) ? 1 : 0;
}

// ---------------- inputs -> fp16 plane (query & kv in one launch) ----------------
__global__ __launch_bounds__(256)
void convert_h(const int* __restrict__ flg,
               const void* __restrict__ q, const void* __restrict__ kv,
               f16* __restrict__ qo, f16* __restrict__ kvo, long n)
{
  const void* in = blockIdx.y ? kv : q;
  f16* out = blockIdx.y ? kvo : qo;
  const long i = ((long)blockIdx.x * 256 + threadIdx.x) * 8;
  if (i >= n) return;
  h8v h;
  if (flg[0] != 0) {
    const float* p = (const float*)in + i;
    f4v f0 = *(const f4v*)p;
    f4v f1 = *(const f4v*)(p + 4);
#pragma unroll
    for (int j = 0; j < 4; ++j) {
      h[j]     = (f16)f0[j];
      h[4 + j] = (f16)f1[j];
    }
  } else {
    s8v b = *(const s8v*)((const short*)in + i);
#pragma unroll
    for (int j = 0; j < 8; ++j) h[j] = (f16)bf2f((u16)b[j]);
  }
  *(h8v*)(out + i) = h;
}

// ---------------- four W^T in one launch: z<3 -> fp16 (Wq,Wk,Wv); z=3 -> bf16 (Wo) ----
__global__ __launch_bounds__(256)
void transpose_w4(const int* __restrict__ flg,
                  const void* __restrict__ w0, const void* __restrict__ w1,
                  const void* __restrict__ w2, const void* __restrict__ w3,
                  f16* __restrict__ h0, f16* __restrict__ h1,
                  f16* __restrict__ h2, u16* __restrict__ b3, int D)
{
  __shared__ float tile[32][33];
  const int zb = blockIdx.z;
  const void* in_v = (zb == 0) ? w0 : (zb == 1) ? w1 : (zb == 2) ? w2 : w3;
  const bool i32 = (flg[0] != 0);
  const u16*   in16 = (const u16*)in_v;
  const float* in32 = (const float*)in_v;
  const int c0 = blockIdx.x * 32, r0 = blockIdx.y * 32;
  const int tx = threadIdx.x, ty = threadIdx.y;   // block (32,8)
  for (int i = ty; i < 32; i += 8) {
    const long idx = (long)(r0 + i) * D + c0 + tx;
    tile[i][tx] = i32 ? in32[idx] : bf2f(in16[idx]);
  }
  __syncthreads();
  f16* outH = (zb == 0) ? h0 : (zb == 1) ? h1 : h2;
  for (int i = ty; i < 32; i += 8) {
    const long idx = (long)(c0 + i) * D + r0 + tx;
    const float v = tile[tx][i];
    if (zb == 3) b3[idx]   = f2bf(v);
    else         outH[idx] = (f16)v;
  }
}

// ---------------- Q/K/V projections in one z=3 dispatch (fp16, BK=64, dbuf) ----------------
__global__ __launch_bounds__(256)
void gemm_proj3(const int* __restrict__ flg,
                const f16* __restrict__ Qi, const f16* __restrict__ KVi,
                const f16* __restrict__ WqT, const f16* __restrict__ WkT,
                const f16* __restrict__ WvT,
                const void* __restrict__ bq, const void* __restrict__ bk,
                const void* __restrict__ bv,
                f16* __restrict__ Qf, f16* __restrict__ Kf,
                u16* __restrict__ Vt, int M, int N, int K, int SB)
{
  __shared__ u16 As[2 * 8192];   // ping-pong buffers
  __shared__ u16 Bs[2 * 8192];

  const int zb = blockIdx.z;
  const f16* A = (zb == 0) ? Qi : KVi;
  const f16* B = (zb == 0) ? WqT : (zb == 1) ? WkT : WvT;
  const void* bias = (zb == 0) ? bq : (zb == 1) ? bk : bv;

  const int f_in = flg[0];
  const int tid = threadIdx.x, lane = tid & 63, wave = tid >> 6;
  const int wm = wave >> 1, wn = wave & 1;
  int bx, by;
  swz_xy(bx, by);
  const int m0 = by * BM, n0 = bx * BN;

  const int rr  = wave * 32 + (lane >> 2);
  const int cc8 = 8 * ((lane & 3) ^ ((lane >> 3) & 3));   // swizzled k-chunk fetch
  const f16* ga00 = A + (long)(m0 + rr) * K + cc8;
  const f16* ga01 = ga00 + 16 * (long)K;
  const f16* gb00 = B + (long)(n0 + rr) * K + cc8;
  const f16* gb01 = gb00 + 16 * (long)K;
  const int l0 = (wave * 2) * 512, l1 = l0 + 512;

  f4v acc[4][4];
#pragma unroll
  for (int i = 0; i < 4; ++i)
#pragma unroll
    for (int j = 0; j < 4; ++j) acc[i][j] = (f4v){0.f, 0.f, 0.f, 0.f};

  const int fr  = lane & 15;
  const int fks = 8 * (((lane >> 4) ^ (lane >> 1)) & 3);  // swizzled fragment offset
  const int aoff = (wm * 64 + fr) * 32 + fks;
  const int boff = (wn * 64 + fr) * 32 + fks;

  const int nIt = K >> 6;
  STAGE8(As, Bs);
  __syncthreads();
  for (int it = 0; it < nIt; ++it) {
    const int cb = (it & 1) * 8192;
    if (it + 1 < nIt) { STAGE8(As + (8192 - cb), Bs + (8192 - cb)); }
    {
      h8v af[4], bfr[4];
#pragma unroll
      for (int mi = 0; mi < 4; ++mi) af[mi]  = *(const h8v*)&As[cb + aoff + mi * 512];
#pragma unroll
      for (int ni = 0; ni < 4; ++ni) bfr[ni] = *(const h8v*)&Bs[cb + boff + ni * 512];
#pragma unroll
      for (int mi = 0; mi < 4; ++mi)
#pragma unroll
        for (int ni = 0; ni < 4; ++ni)
          acc[mi][ni] = __builtin_amdgcn_mfma_f32_16x16x32_f16(af[mi], bfr[ni], acc[mi][ni], 0, 0, 0);
    }
    {
      h8v af[4], bfr[4];
#pragma unroll
      for (int mi = 0; mi < 4; ++mi) af[mi]  = *(const h8v*)&As[cb + 4096 + aoff + mi * 512];
#pragma unroll
      for (int ni = 0; ni < 4; ++ni) bfr[ni] = *(const h8v*)&Bs[cb + 4096 + boff + ni * 512];
#pragma unroll
      for (int mi = 0; mi < 4; ++mi)
#pragma unroll
        for (int ni = 0; ni < 4; ++ni)
          acc[mi][ni] = __builtin_amdgcn_mfma_f32_16x16x32_f16(af[mi], bfr[ni], acc[mi][ni], 0, 0, 0);
    }
    __syncthreads();
  }

  const int cr = (lane >> 4) * 4, ccl = lane & 15;
  if (zb < 2) {
    f16* out = zb ? Kf : Qf;
#pragma unroll
    for (int ni = 0; ni < 4; ++ni) {
      const int gcol = n0 + wn * 64 + ni * 16 + ccl;
      const float bvv = (f_in != 0) ? ((const float*)bias)[gcol]
                                    : bf2f(((const u16*)bias)[gcol]);
#pragma unroll
      for (int mi = 0; mi < 4; ++mi)
#pragma unroll
        for (int r = 0; r < 4; ++r) {
          const long grow = (long)(m0 + wm * 64 + mi * 16 + cr + r);
          out[grow * N + gcol] = (f16)(acc[mi][ni][r] + bvv);
        }
    }
  } else {
    // transposed epilogue through dead staging LDS (4 waves x 2176 u16 in As)
    u16* xw = &As[wave * 2176];
    const int b  = m0 / SB;
    const int s0 = (m0 % SB) + wm * 64;
    const long bbase = (long)b * N * SB;
#pragma unroll
    for (int h = 0; h < 2; ++h) {
#pragma unroll
      for (int nl = 0; nl < 2; ++nl) {
        const int ni = h * 2 + nl;
        const int gcol = n0 + wn * 64 + ni * 16 + ccl;
        const float bvv = (f_in != 0) ? ((const float*)bias)[gcol]
                                      : bf2f(((const u16*)bias)[gcol]);
#pragma unroll
        for (int mi = 0; mi < 4; ++mi)
#pragma unroll
          for (int r = 0; r < 4; ++r)
            xw[(mi * 16 + cr + r) * 34 + nl * 16 + ccl] = f2bf(acc[mi][ni][r] + bvv);
      }
      __syncthreads();
#pragma unroll
      for (int c = 0; c < 32; ++c) {
        const int gcol = n0 + wn * 64 + h * 32 + c;
        Vt[bbase + (long)gcol * SB + s0 + lane] = xw[lane * 34 + c];
      }
      __syncthreads();
    }
  }
}

// ---------------- scores GEMM: fp16, BK=64, dbuf, fp32 out, z-batched ----------------
__global__ __launch_bounds__(256)
void gemm_sc64(const f16* __restrict__ A, const f16* __restrict__ B,
               float* __restrict__ C, int M, int N, int K,
               long sA, long sB, long sC)
{
  __shared__ u16 As[2 * 8192];
  __shared__ u16 Bs[2 * 8192];

  const int tid = threadIdx.x, lane = tid & 63, wave = tid >> 6;
  const int wm = wave >> 1, wn = wave & 1;
  int bx, by;
  swz_xy(bx, by);
  const int m0 = by * BM, n0 = bx * BN;
  const long z = blockIdx.z;

  const int rr  = wave * 32 + (lane >> 2);
  const int cc8 = 8 * ((lane & 3) ^ ((lane >> 3) & 3));
  const f16* ga00 = A + (long)(m0 + rr) * K + cc8 + z * sA;
  const f16* ga01 = ga00 + 16 * (long)K;
  const f16* gb00 = B + (long)(n0 + rr) * K + cc8 + z * sB;
  const f16* gb01 = gb00 + 16 * (long)K;
  const int l0 = (wave * 2) * 512, l1 = l0 + 512;

  f4v acc[4][4];
#pragma unroll
  for (int i = 0; i < 4; ++i)
#pragma unroll
    for (int j = 0; j < 4; ++j) acc[i][j] = (f4v){0.f, 0.f, 0.f, 0.f};

  const int fr  = lane & 15;
  const int fks = 8 * (((lane >> 4) ^ (lane >> 1)) & 3);
  const int aoff = (wm * 64 + fr) * 32 + fks;
  const int boff = (wn * 64 + fr) * 32 + fks;

  const int nIt = K >> 6;
  STAGE8(As, Bs);
  __syncthreads();
  for (int it = 0; it < nIt; ++it) {
    const int cb = (it & 1) * 8192;
    if (it + 1 < nIt) { STAGE8(As + (8192 - cb), Bs + (8192 - cb)); }
    {
      h8v af[4], bfr[4];
#pragma unroll
      for (int mi = 0; mi < 4; ++mi) af[mi]  = *(const h8v*)&As[cb + aoff + mi * 512];
#pragma unroll
      for (int ni = 0; ni < 4; ++ni) bfr[ni] = *(const h8v*)&Bs[cb + boff + ni * 512];
#pragma unroll
      for (int mi = 0; mi < 4; ++mi)
#pragma unroll
        for (int ni = 0; ni < 4; ++ni)
          acc[mi][ni] = __builtin_amdgcn_mfma_f32_16x16x32_f16(af[mi], bfr[ni], acc[mi][ni], 0, 0, 0);
    }
    {
      h8v af[4], bfr[4];
#pragma unroll
      for (int mi = 0; mi < 4; ++mi) af[mi]  = *(const h8v*)&As[cb + 4096 + aoff + mi * 512];
#pragma unroll
      for (int ni = 0; ni < 4; ++ni) bfr[ni] = *(const h8v*)&Bs[cb + 4096 + boff + ni * 512];
#pragma unroll
      for (int mi = 0; mi < 4; ++mi)
#pragma unroll
        for (int ni = 0; ni < 4; ++ni)
          acc[mi][ni] = __builtin_amdgcn_mfma_f32_16x16x32_f16(af[mi], bfr[ni], acc[mi][ni], 0, 0, 0);
    }
    __syncthreads();
  }

  const int cr = (lane >> 4) * 4, ccl = lane & 15;
#pragma unroll
  for (int ni = 0; ni < 4; ++ni) {
    const int gcol = n0 + wn * 64 + ni * 16 + ccl;
#pragma unroll
    for (int mi = 0; mi < 4; ++mi)
#pragma unroll
      for (int r = 0; r < 4; ++r) {
        const long grow = (long)(m0 + wm * 64 + mi * 16 + cr + r);
        C[z * sC + grow * N + gcol] = acc[mi][ni][r];
      }
  }
}

// ---------------- bf16 NT GEMM, BK=64, dbuf (PV, out-proj) ----------------
template<bool OUT_FLAG, bool HAS_BIAS>
__global__ __launch_bounds__(256)
void gemm_bf64(const int* __restrict__ flg, const u16* __restrict__ A,
               const u16* __restrict__ Bt, const void* __restrict__ bias,
               void* __restrict__ Cv, int M, int N, int K,
               long sA, long sB, long sC)
{
  __shared__ u16 As[2 * 8192];
  __shared__ u16 Bs[2 * 8192];

  const int f_in = flg[0];
  const int tid = threadIdx.x, lane = tid & 63, wave = tid >> 6;
  const int wm = wave >> 1, wn = wave & 1;
  int bx, by;
  swz_xy(bx, by);
  const int m0 = by * BM, n0 = bx * BN;
  const long z = blockIdx.z;

  const int rr  = wave * 32 + (lane >> 2);
  const int cc8 = 8 * ((lane & 3) ^ ((lane >> 3) & 3));
  const u16* ga00 = A + (long)(m0 + rr) * K + cc8 + z * sA;
  const u16* ga01 = ga00 + 16 * (long)K;
  const u16* gb00 = Bt + (long)(n0 + rr) * K + cc8 + z * sB;
  const u16* gb01 = gb00 + 16 * (long)K;
  const int l0 = (wave * 2) * 512, l1 = l0 + 512;

  f4v acc[4][4];
#pragma unroll
  for (int i = 0; i < 4; ++i)
#pragma unroll
    for (int j = 0; j < 4; ++j) acc[i][j] = (f4v){0.f, 0.f, 0.f, 0.f};

  const int fr  = lane & 15;
  const int fks = 8 * (((lane >> 4) ^ (lane >> 1)) & 3);
  const int aoff = (wm * 64 + fr) * 32 + fks;
  const int boff = (wn * 64 + fr) * 32 + fks;

  const int nIt = K >> 6;
  STAGE8(As, Bs);
  __syncthreads();
  for (int it = 0; it < nIt; ++it) {
    const int cb = (it & 1) * 8192;
    if (it + 1 < nIt) { STAGE8(As + (8192 - cb), Bs + (8192 - cb)); }
    {
      s8v af[4], bfr[4];
#pragma unroll
      for (int mi = 0; mi < 4; ++mi) af[mi]  = *(const s8v*)&As[cb + aoff + mi * 512];
#pragma unroll
      for (int ni = 0; ni < 4; ++ni) bfr[ni] = *(const s8v*)&Bs[cb + boff + ni * 512];
#pragma unroll
      for (int mi = 0; mi < 4; ++mi)
#pragma unroll
        for (int ni = 0; ni < 4; ++ni)
          acc[mi][ni] = __builtin_amdgcn_mfma_f32_16x16x32_bf16(af[mi], bfr[ni], acc[mi][ni], 0, 0, 0);
    }
    {
      s8v af[4], bfr[4];
#pragma unroll
      for (int mi = 0; mi < 4; ++mi) af[mi]  = *(const s8v*)&As[cb + 4096 + aoff + mi * 512];
#pragma unroll
      for (int ni = 0; ni < 4; ++ni) bfr[ni] = *(const s8v*)&Bs[cb + 4096 + boff + ni * 512];
#pragma unroll
      for (int mi = 0; mi < 4; ++mi)
#pragma unroll
        for (int ni = 0; ni < 4; ++ni)
          acc[mi][ni] = __builtin_amdgcn_mfma_f32_16x16x32_bf16(af[mi], bfr[ni], acc[mi][ni], 0, 0, 0);
    }
    __syncthreads();
  }

  const int cr = (lane >> 4) * 4, ccl = lane & 15;
  const bool o32 = OUT_FLAG && (f_in != 0);
#pragma unroll
  for (int ni = 0; ni < 4; ++ni) {
    const int gcol = n0 + wn * 64 + ni * 16 + ccl;
    float bvv = 0.f;
    if (HAS_BIAS)
      bvv = (f_in != 0) ? ((const float*)bias)[gcol] : bf2f(((const u16*)bias)[gcol]);
#pragma unroll
    for (int mi = 0; mi < 4; ++mi)
#pragma unroll
      for (int r = 0; r < 4; ++r) {
        const long grow = (long)(m0 + wm * 64 + mi * 16 + cr + r);
        const float val = acc[mi][ni][r] + bvv;
        const long idx = z * sC + grow * N + gcol;
        if (o32) ((float*)Cv)[idx] = val;
        else     ((u16*)Cv)[idx]   = f2bf(val);
      }
  }
}

// ---------------- row softmax fp32 -> bf16 attn, N=2048, one block/row ----------------
__global__ __launch_bounds__(256)
void softmax_rows_bf(const float* __restrict__ S, u16* __restrict__ P, int N)
{
  const float* row = S + (long)blockIdx.x * N;
  u16* prow = P + (long)blockIdx.x * N;
  const int t = threadIdx.x;
  f4v v0 = *(const f4v*)(row + t * 8);
  f4v v1 = *(const f4v*)(row + t * 8 + 4);

  float m = v0[0];
#pragma unroll
  for (int j = 1; j < 4; ++j) m = fmaxf(m, v0[j]);
#pragma unroll
  for (int j = 0; j < 4; ++j) m = fmaxf(m, v1[j]);
  for (int off = 32; off > 0; off >>= 1) m = fmaxf(m, __shfl_down(m, off, 64));

  __shared__ float redm[4], reds[4];
  if ((t & 63) == 0) redm[t >> 6] = m;
  __syncthreads();
  m = fmaxf(fmaxf(redm[0], redm[1]), fmaxf(redm[2], redm[3]));

  float s = 0.f;
#pragma unroll
  for (int j = 0; j < 4; ++j) { v0[j] = __expf(v0[j] - m); s += v0[j]; }
#pragma unroll
  for (int j = 0; j < 4; ++j) { v1[j] = __expf(v1[j] - m); s += v1[j]; }
  for (int off = 32; off > 0; off >>= 1) s += __shfl_down(s, off, 64);
  if ((t & 63) == 0) reds[t >> 6] = s;
  __syncthreads();
  s = reds[0] + reds[1] + reds[2] + reds[3];

  const float inv = 1.f / s;
  s8v o;
#pragma unroll
  for (int j = 0; j < 4; ++j) {
    o[j]     = (short)f2bf(v0[j] * inv);
    o[4 + j] = (short)f2bf(v1[j] * inv);
  }
  *(s8v*)(prow + t * 8) = o;
}

extern "C" void kernel_launch(void* const* d_in, const int* in_sizes, int n_in,
                              void* d_out, int out_size, void* d_ws, size_t ws_size,
                              hipStream_t stream)
{
  const void* query = d_in[0];
  const void* kv    = d_in[1];
  const void* Wq    = d_in[2];
  const void* bq    = d_in[3];
  const void* Wk    = d_in[4];
  const void* bk    = d_in[5];
  const void* Wv    = d_in[6];
  const void* bv    = d_in[7];
  const void* Wo    = d_in[8];
  const void* bo    = d_in[9];

  const int Bn = 4, S = 2048, D = 1024;
  const int MS = Bn * S;                       // 8192
  const size_t KBu = 1024, MBu = 1024 * 1024;
  const long nTok = (long)MS * D;

  // ---- workspace layout (~168 MB; ws proven >= 173 MB) ----
  char* ws = (char*)d_ws;
  int*  flg  = (int*)(ws);
  f16*  Qi   = (f16*)(ws + 64 * KBu);          // 16MB fp16 input tokens
  f16*  KVi  = (f16*)(ws + 64 * KBu + 16 * MBu);
  char* rW   = ws + 64 * KBu + 32 * MBu;       // 8MB: W^T
  f16*  WqT  = (f16*)(rW);
  f16*  WkT  = (f16*)(rW + 2 * MBu);
  f16*  WvT  = (f16*)(rW + 4 * MBu);
  u16*  WoT  = (u16*)(rW + 6 * MBu);
  char* rQK  = rW + 8 * MBu;                   // 32MB: Q,K fp16; later attn bf16
  f16*  Qf   = (f16*)(rQK);
  f16*  Kf   = (f16*)(rQK + 16 * MBu);
  u16*  attn = (u16*)(rQK);                    // 32MB (Q/K dead after scores)
  float* Sc  = (float*)(rQK + 32 * MBu);       // 64MB fp32 scores
  char* rV   = rQK + 96 * MBu;                 // 32MB
  u16*  Vt   = (u16*)(rV);                     // [B][D][S] bf16
  u16*  Cx   = (u16*)(rV + 16 * MBu);          // [B][S][D] bf16

  detect_dtype<<<1, 256, 0, stream>>>((const u16*)query, flg);

  convert_h<<<dim3((unsigned)(nTok / 2048), 2), 256, 0, stream>>>(
      flg, query, kv, Qi, KVi, nTok);

  dim3 tb(32, 8);
  transpose_w4<<<dim3(32, 32, 4), tb, 0, stream>>>(
      flg, Wq, Wk, Wv, Wo, WqT, WkT, WvT, WoT, D);

  // Q, K, V projections in one dispatch (V -> Vt transposed)
  gemm_proj3<<<dim3(D / BN, MS / BM, 3), 256, 0, stream>>>(
      flg, Qi, KVi, WqT, WkT, WvT, bq, bk, bv, Qf, Kf, Vt, MS, D, D, S);

  // scores (fp16, fp32 out), softmax -> bf16 attn, PV (bf16)
  gemm_sc64<<<dim3(S / BN, S / BM, Bn), 256, 0, stream>>>(
      Qf, Kf, Sc, S, S, D, (long)S * D, (long)S * D, (long)S * S);
  softmax_rows_bf<<<dim3(Bn * S), 256, 0, stream>>>(Sc, attn, S);
  gemm_bf64<false, false><<<dim3(D / BN, S / BM, Bn), 256, 0, stream>>>(
      flg, attn, Vt, nullptr, Cx, S, D, S, (long)S * S, (long)D * S, (long)S * D);

  // output projection -> d_out (dtype per flag)
  gemm_bf64<true, true><<<dim3(D / BN, MS / BM, 1), 256, 0, stream>>>(
      flg, Cx, WoT, bo, d_out, MS, D, D, 0L, 0L, 0L);
}